// Round 10
// baseline (2376.133 us; speedup 1.0000x reference)
//
#include <hip/hip_runtime.h>
#include <math.h>
#include <stdint.h>

#define NB 8
#define NN 1024
#define DD 256
#define NP1 1025
#define LDC 1028   // cfin row stride (floats)
#define NSTEPS 100

// ---------------------------------------------------------------- norms ----
__global__ __launch_bounds__(256) void norm_kernel(const float* __restrict__ fA,
                                                   const float* __restrict__ fB,
                                                   float* __restrict__ invA,
                                                   float* __restrict__ invB) {
  int gw = (blockIdx.x * 256 + threadIdx.x) >> 6;  // global wave id, 0..16383
  int lane = threadIdx.x & 63;
  const float* src;
  float* dst;
  int row;
  if (gw < NB * NN) { src = fA; dst = invA; row = gw; }
  else              { src = fB; dst = invB; row = gw - NB * NN; }
  float4 v = *(const float4*)(src + (size_t)row * DD + lane * 4);
  double ss = (double)v.x * v.x + (double)v.y * v.y + (double)v.z * v.z + (double)v.w * v.w;
#pragma unroll
  for (int o = 32; o; o >>= 1) ss += __shfl_xor(ss, o, 64);
  if (lane == 0) dst[row] = (float)(1.0 / sqrt(fmax(ss, 1e-12)));
}

// ------------------------------------------------ GEMM + exp + partial Z ---
// Stores ONLY the 1024x1024 body (stride 1024); dustbin handled analytically.
__global__ __launch_bounds__(256) void gemm_exp_kernel(const float* __restrict__ fA,
                                                       const float* __restrict__ fB,
                                                       const float* __restrict__ invA,
                                                       const float* __restrict__ invB,
                                                       float* __restrict__ P0,
                                                       double* __restrict__ partZ) {
  const int id = blockIdx.x;
  const int b = id & 7;
  const int tile = id >> 3;
  const int bx = tile & 15, by = tile >> 4;
  const int row0 = by * 64, col0 = bx * 64;
  const int tid = threadIdx.x;
  const int tx = tid & 15, ty = tid >> 4;
  __shared__ __align__(16) float As[16][68];
  __shared__ __align__(16) float Bs[16][68];
  __shared__ double zred[256];
  float acc[4][4] = {{0.f}};
  const int lm = tid >> 2, kq = (tid & 3) << 2;
  const float sa = invA[b * NN + row0 + lm];
  const float sb = invB[b * NN + col0 + lm];
  const float* pA = fA + (size_t)(b * NN + row0 + lm) * DD + kq;
  const float* pB = fB + (size_t)(b * NN + col0 + lm) * DD + kq;
  for (int k0 = 0; k0 < DD; k0 += 16) {
    const float4 a4 = *(const float4*)(pA + k0);
    const float4 b4 = *(const float4*)(pB + k0);
    As[kq + 0][lm] = a4.x * sa; As[kq + 1][lm] = a4.y * sa;
    As[kq + 2][lm] = a4.z * sa; As[kq + 3][lm] = a4.w * sa;
    Bs[kq + 0][lm] = b4.x * sb; Bs[kq + 1][lm] = b4.y * sb;
    Bs[kq + 2][lm] = b4.z * sb; Bs[kq + 3][lm] = b4.w * sb;
    __syncthreads();
#pragma unroll
    for (int kk = 0; kk < 16; ++kk) {
      const float4 av = *(const float4*)&As[kk][ty * 4];
      const float4 bv = *(const float4*)&Bs[kk][tx * 4];
      const float ar[4] = {av.x, av.y, av.z, av.w};
      const float br[4] = {bv.x, bv.y, bv.z, bv.w};
#pragma unroll
      for (int a = 0; a < 4; ++a)
#pragma unroll
        for (int e = 0; e < 4; ++e)
          acc[a][e] = fmaf(ar[a], br[e], acc[a][e]);
    }
    __syncthreads();
  }
  // exp(5*clip(S,-3,3)) == exp(-5*clip(-S,-3,3))  (matches reference exactly)
  double zs = 0.0;
#pragma unroll
  for (int a = 0; a < 4; ++a)
#pragma unroll
    for (int e = 0; e < 4; ++e) {
      const float S = acc[a][e];
      const float C = fminf(fmaxf(-S, -3.0f), 3.0f);
      const float p = expf(-5.0f * C);
      acc[a][e] = p;
      zs += (double)p;
    }
  {
    float* P0b = P0 + (size_t)b * NN * NN;
#pragma unroll
    for (int a = 0; a < 4; ++a) {
      float4 v;
      v.x = acc[a][0]; v.y = acc[a][1]; v.z = acc[a][2]; v.w = acc[a][3];
      *(float4*)(P0b + (size_t)(row0 + ty * 4 + a) * NN + col0 + tx * 4) = v;
    }
  }
  zred[tid] = zs;
  __syncthreads();
#pragma unroll
  for (int o = 128; o; o >>= 1) {
    if (tid < o) zred[tid] += zred[tid + o];
    __syncthreads();
  }
  if (tid == 0) partZ[(b * 16 + by) * 16 + bx] = zred[0];
}

// ------------------------------------------------------- init r0, B bufs ---
__global__ __launch_bounds__(256) void init_rc_kernel(const double* __restrict__ partZ,
                                                      float* __restrict__ r0,
                                                      double* __restrict__ Binit,
                                                      double* __restrict__ Bzero) {
  const int b = blockIdx.x, tid = threadIdx.x;
  __shared__ double red[256];
  red[tid] = partZ[b * 256 + tid];
  __syncthreads();
#pragma unroll
  for (int o = 128; o; o >>= 1) {
    if (tid < o) red[tid] += red[tid + o];
    __syncthreads();
  }
  const double Z = red[0];
  const float rv = (float)(1.0 / Z);
  for (int i = tid; i < NP1; i += 256) {
    r0[b * NP1 + i] = rv;
    Binit[b * NP1 + i] = (i == NN) ? (double)NN : 1.0;  // so c_0 = ab/Binit = 1
    Bzero[b * NP1 + i] = 0.0;
  }
}

// --------------------------------------------- one Sinkhorn step kernel ----
// Body-only P0 (b = id%8 XCD pin). Wave layout: wq = column quadrant (256
// cols, float4/lane), wh = row half (8 rows). Column partials are
// wave-exclusive per quadrant -> one 4KB LDS exchange between halves; row
// dots reduce via a 512B f64 LDS array. c is computed IN REGISTERS (each
// lane divides exactly the 4 Bprev values it needs). One __syncthreads.
//   u_i = body_i . c + dv*c_N          -> r'_i = 1/u_i
//   u_N = dv*(sum(c)+c_N)              -> r'_N = N/u_N        (desig block)
//   B_j = colsum(r .* body)_j + r_N*dv (desig adds the r_N*dv term)
//   B_N = dv*(sum(r) + r_N)
__global__ __launch_bounds__(512, 4) void step_kernel(const float* __restrict__ P0,
                                                      const float* __restrict__ dustbin,
                                                      const float* __restrict__ rin,
                                                      float* __restrict__ rout,
                                                      const double* __restrict__ Bprev,
                                                      double* __restrict__ Bacc,
                                                      double* __restrict__ Bzero) {
  const int id = blockIdx.x;
  const int b = id & 7;   // XCD pin
  const int s = id >> 3;  // slab 0..63 -> rows s*16..s*16+15
  const int tid = threadIdx.x;
  const int lane = tid & 63;
  const int wv = tid >> 6;    // 0..7
  const int wq = wv & 3;      // column quadrant
  const int wh = wv >> 2;     // row half
  const bool desig = (s == 63);
  const int row0 = s * 16;
  const int col0 = wq * 256 + lane * 4;

  __shared__ __align__(16) float qlds[1024];
  __shared__ double dred[16][4];
  __shared__ double csum_lds[4];
  __shared__ double rs_lds[2];
  __shared__ double cN_sh;

  const float d = dustbin[0];
  const float dv = expf(-5.0f * fminf(fmaxf(-d, -3.0f), 3.0f));
  const double dv_d = (double)dv;

  const float* P0b = P0 + (size_t)b * NN * NN;
  const float* rv_in = rin + b * NP1;
  const double* Bp = Bprev + b * NP1;

  // ---- issue all loads first ----
  float4 p[8];
#pragma unroll
  for (int q = 0; q < 8; ++q)
    p[q] = *(const float4*)(P0b + (size_t)(row0 + wh * 8 + q) * NN + col0);
  const double bd0 = Bp[col0 + 0], bd1 = Bp[col0 + 1];
  const double bd2 = Bp[col0 + 2], bd3 = Bp[col0 + 3];
  float rw[8];
#pragma unroll
  for (int q = 0; q < 8; ++q) rw[q] = rv_in[row0 + wh * 8 + q];  // wave-uniform

  // zero next-step B (512 x 17 = 8704 >= 8200)
  if (tid < 17) {
    const int idx = id * 17 + tid;
    if (idx < NB * NP1) Bzero[idx] = 0.0;
  }
  if (tid == 0) cN_sh = (double)NN / Bp[NN];

  // c in registers: f32 values (matching R9 numerics), used as f64 in dots
  const float cf0 = (float)(1.0 / bd0), cf1 = (float)(1.0 / bd1);
  const float cf2 = (float)(1.0 / bd2), cf3 = (float)(1.0 / bd3);
  const double c0 = (double)cf0, c1 = (double)cf1;
  const double c2 = (double)cf2, c3 = (double)cf3;

  // ---- fused: 8 row-dot partials (f64) + column partials (f32) ----
  double dq[8];
  float4 qacc = {0.f, 0.f, 0.f, 0.f};
#pragma unroll
  for (int q = 0; q < 8; ++q) {
    dq[q] = (double)p[q].x * c0 + (double)p[q].y * c1 +
            (double)p[q].z * c2 + (double)p[q].w * c3;
    qacc.x = fmaf(rw[q], p[q].x, qacc.x);
    qacc.y = fmaf(rw[q], p[q].y, qacc.y);
    qacc.z = fmaf(rw[q], p[q].z, qacc.z);
    qacc.w = fmaf(rw[q], p[q].w, qacc.w);
  }
#pragma unroll
  for (int o = 32; o; o >>= 1) {
#pragma unroll
    for (int q = 0; q < 8; ++q) dq[q] += __shfl_xor(dq[q], o, 64);
  }
  if (lane == 0) {
#pragma unroll
    for (int q = 0; q < 8; ++q) dred[wh * 8 + q][wq] = dq[q];
  }
  if (wh == 0) {
    // csum over body columns (waves 0..3 cover all 1024 cols exactly once)
    double cs = (c0 + c1) + (c2 + c3);
#pragma unroll
    for (int o = 32; o; o >>= 1) cs += __shfl_xor(cs, o, 64);
    if (lane == 0) csum_lds[wq] = cs;
    *(float4*)&qlds[col0] = qacc;  // stage half-0 partials for half-1 combine
  }
  if ((wv == 0 || wv == 4) && lane == 0) {
    double rs = 0.0;
#pragma unroll
    for (int q = 0; q < 8; ++q) rs += (double)rw[q];
    rs_lds[wh] = rs;
  }
  __syncthreads();

  const double cN = cN_sh;
  float* ro = rout + b * NP1;
  double* Ba = Bacc + b * NP1;
  if (tid < 16) {
    const double dot = ((dred[tid][0] + dred[tid][1]) +
                        (dred[tid][2] + dred[tid][3])) + dv_d * cN;
    ro[row0 + tid] = (float)(1.0 / dot);
  } else if (tid == 16) {
    double rsum = rs_lds[0] + rs_lds[1];
    if (desig) rsum += (double)rv_in[NN];
    atomicAdd(Ba + NN, dv_d * rsum);  // B_N = dv * sum(r)
  } else if (tid == 17 && desig) {
    const double sc = ((csum_lds[0] + csum_lds[1]) +
                       (csum_lds[2] + csum_lds[3])) + cN;
    ro[NN] = (float)((double)NN / (dv_d * sc));  // r'_N
  }
  if (wh == 1) {
    float4 qo = *(const float4*)&qlds[col0];
    qo.x += qacc.x; qo.y += qacc.y; qo.z += qacc.z; qo.w += qacc.w;
    if (desig) {
      const float rNdv = rv_in[NN] * dv;  // dustbin-row contribution, once/batch
      qo.x += rNdv; qo.y += rNdv; qo.z += rNdv; qo.w += rNdv;
    }
    atomicAdd(Ba + col0 + 0, (double)qo.x);
    atomicAdd(Ba + col0 + 1, (double)qo.y);
    atomicAdd(Ba + col0 + 2, (double)qo.z);
    atomicAdd(Ba + col0 + 3, (double)qo.w);
  }
}

// ----------------------------------------------------- final c from B ------
__global__ __launch_bounds__(256) void cfinal_kernel(const double* __restrict__ Bfin,
                                                     float* __restrict__ cfin) {
  const int b = blockIdx.x;
  for (int j = threadIdx.x; j < NP1; j += 256)
    cfin[b * LDC + j] = (float)(((j == NN) ? (double)NN : 1.0) / Bfin[b * NP1 + j]);
}

// --------------------------------------------------------------- finalize --
// One row per block; body rows from ws (stride 1024), dustbin row/col = dv.
__global__ __launch_bounds__(256) void finalize_kernel(const float* __restrict__ P0,
                                                       const float* __restrict__ dustbin,
                                                       float* __restrict__ Pout,
                                                       const float* __restrict__ rfin,
                                                       const float* __restrict__ cfin) {
  const int bi = blockIdx.x;
  const int b = bi & 7, i = bi >> 3;  // XCD pin
  const int tid = threadIdx.x;
  const float d = dustbin[0];
  const float dv = expf(-5.0f * fminf(fmaxf(-d, -3.0f), 3.0f));
  const float4* cv = (const float4*)(cfin + b * LDC);
  const float cN = cfin[b * LDC + NN];
  float* dst = Pout + (size_t)b * NP1 * NP1 + (size_t)i * NP1;
  const float4 c = cv[tid];
  if (i < NN) {
    const float rv = rfin[b * NP1 + i];
    const float4 p = ((const float4*)(P0 + ((size_t)b * NN + i) * NN))[tid];
    dst[tid * 4 + 0] = rv * p.x * c.x;
    dst[tid * 4 + 1] = rv * p.y * c.y;
    dst[tid * 4 + 2] = rv * p.z * c.z;
    dst[tid * 4 + 3] = rv * p.w * c.w;
    if (tid == 0) dst[NN] = rv * dv * cN;
  } else {
    const float rv = rfin[b * NP1 + NN];
    dst[tid * 4 + 0] = rv * dv * c.x;
    dst[tid * 4 + 1] = rv * dv * c.y;
    dst[tid * 4 + 2] = rv * dv * c.z;
    dst[tid * 4 + 3] = rv * dv * c.w;
    if (tid == 0) dst[NN] = rv * dv * cN;
  }
}

// ---------------------------------------------------------------------------
extern "C" void kernel_launch(void* const* d_in, const int* in_sizes, int n_in,
                              void* d_out, int out_size, void* d_ws, size_t ws_size,
                              hipStream_t stream) {
  const float* fA = (const float*)d_in[0];
  const float* fB = (const float*)d_in[1];
  const float* dustbin = (const float*)d_in[2];

  float* Pout = (float*)d_out;

  float* P0 = (float*)d_ws;                    // [8][1024][1024] f32 body (32 MiB)
  float* rbuf = P0 + (size_t)NB * NN * NN;     // [2][8][1025] f32
  float* cfin = rbuf + 2 * NB * NP1;           // [8][1028] f32
  double* Bbuf = (double*)(((uintptr_t)(cfin + NB * LDC) + 15) & ~(uintptr_t)15);  // [3][8][1025] f64
  double* partZ = Bbuf + 3 * NB * NP1;         // [8][256] f64
  float* invA = (float*)(partZ + NB * 256);    // [8][1024]
  float* invB = invA + NB * NN;                // [8][1024]

  norm_kernel<<<4096, 256, 0, stream>>>(fA, fB, invA, invB);
  gemm_exp_kernel<<<2048, 256, 0, stream>>>(fA, fB, invA, invB, P0, partZ);
  // r_0 -> rbuf[0]; B "prev" for t=0 -> Bbuf[2] (c_0 = 1); zero Bbuf[0]
  init_rc_kernel<<<NB, 256, 0, stream>>>(partZ, rbuf, Bbuf + 2 * NB * NP1, Bbuf);

  // step t: reads r[t%2], B[(t+2)%3]; writes r[(t+1)%2]; accumulates B[t%3];
  //         zeroes B[(t+1)%3] (for step t+1).
  for (int t = 0; t < NSTEPS; ++t) {
    float* rin = rbuf + (t & 1) * NB * NP1;
    float* rout = rbuf + ((t + 1) & 1) * NB * NP1;
    double* Bprev = Bbuf + ((t + 2) % 3) * NB * NP1;
    double* Bacc = Bbuf + (t % 3) * NB * NP1;
    double* Bzero = Bbuf + ((t + 1) % 3) * NB * NP1;
    step_kernel<<<512, 512, 0, stream>>>(P0, dustbin, rin, rout, Bprev, Bacc, Bzero);
  }

  // after t=99: r_100 in rbuf[0]; B_99 (col sums) in Bbuf[99%3=0]
  cfinal_kernel<<<NB, 256, 0, stream>>>(Bbuf, cfin);
  finalize_kernel<<<NB * NP1, 256, 0, stream>>>(P0, dustbin, Pout, rbuf, cfin);
}

// Round 11
// 888.372 us; speedup vs baseline: 2.6747x; 2.6747x over previous
//
#include <hip/hip_runtime.h>
#include <math.h>
#include <stdint.h>

#define NB 8
#define NN 1024
#define DD 256
#define NP1 1025
#define LDC 1028   // cfin row stride (floats)
#define NSTEPS 100

// ---------------------------------------------------------------- norms ----
__global__ __launch_bounds__(256) void norm_kernel(const float* __restrict__ fA,
                                                   const float* __restrict__ fB,
                                                   float* __restrict__ invA,
                                                   float* __restrict__ invB) {
  int gw = (blockIdx.x * 256 + threadIdx.x) >> 6;  // global wave id, 0..16383
  int lane = threadIdx.x & 63;
  const float* src;
  float* dst;
  int row;
  if (gw < NB * NN) { src = fA; dst = invA; row = gw; }
  else              { src = fB; dst = invB; row = gw - NB * NN; }
  float4 v = *(const float4*)(src + (size_t)row * DD + lane * 4);
  double ss = (double)v.x * v.x + (double)v.y * v.y + (double)v.z * v.z + (double)v.w * v.w;
#pragma unroll
  for (int o = 32; o; o >>= 1) ss += __shfl_xor(ss, o, 64);
  if (lane == 0) dst[row] = (float)(1.0 / sqrt(fmax(ss, 1e-12)));
}

// ------------------------------------------------ GEMM + exp + partial Z ---
// Stores ONLY the 1024x1024 body (stride 1024); dustbin handled analytically.
__global__ __launch_bounds__(256) void gemm_exp_kernel(const float* __restrict__ fA,
                                                       const float* __restrict__ fB,
                                                       const float* __restrict__ invA,
                                                       const float* __restrict__ invB,
                                                       float* __restrict__ P0,
                                                       double* __restrict__ partZ) {
  const int id = blockIdx.x;
  const int b = id & 7;
  const int tile = id >> 3;
  const int bx = tile & 15, by = tile >> 4;
  const int row0 = by * 64, col0 = bx * 64;
  const int tid = threadIdx.x;
  const int tx = tid & 15, ty = tid >> 4;
  __shared__ __align__(16) float As[16][68];
  __shared__ __align__(16) float Bs[16][68];
  __shared__ double zred[256];
  float acc[4][4] = {{0.f}};
  const int lm = tid >> 2, kq = (tid & 3) << 2;
  const float sa = invA[b * NN + row0 + lm];
  const float sb = invB[b * NN + col0 + lm];
  const float* pA = fA + (size_t)(b * NN + row0 + lm) * DD + kq;
  const float* pB = fB + (size_t)(b * NN + col0 + lm) * DD + kq;
  for (int k0 = 0; k0 < DD; k0 += 16) {
    const float4 a4 = *(const float4*)(pA + k0);
    const float4 b4 = *(const float4*)(pB + k0);
    As[kq + 0][lm] = a4.x * sa; As[kq + 1][lm] = a4.y * sa;
    As[kq + 2][lm] = a4.z * sa; As[kq + 3][lm] = a4.w * sa;
    Bs[kq + 0][lm] = b4.x * sb; Bs[kq + 1][lm] = b4.y * sb;
    Bs[kq + 2][lm] = b4.z * sb; Bs[kq + 3][lm] = b4.w * sb;
    __syncthreads();
#pragma unroll
    for (int kk = 0; kk < 16; ++kk) {
      const float4 av = *(const float4*)&As[kk][ty * 4];
      const float4 bv = *(const float4*)&Bs[kk][tx * 4];
      const float ar[4] = {av.x, av.y, av.z, av.w};
      const float br[4] = {bv.x, bv.y, bv.z, bv.w};
#pragma unroll
      for (int a = 0; a < 4; ++a)
#pragma unroll
        for (int e = 0; e < 4; ++e)
          acc[a][e] = fmaf(ar[a], br[e], acc[a][e]);
    }
    __syncthreads();
  }
  // exp(5*clip(S,-3,3)) == exp(-5*clip(-S,-3,3))  (matches reference exactly)
  double zs = 0.0;
#pragma unroll
  for (int a = 0; a < 4; ++a)
#pragma unroll
    for (int e = 0; e < 4; ++e) {
      const float S = acc[a][e];
      const float C = fminf(fmaxf(-S, -3.0f), 3.0f);
      const float p = expf(-5.0f * C);
      acc[a][e] = p;
      zs += (double)p;
    }
  {
    float* P0b = P0 + (size_t)b * NN * NN;
#pragma unroll
    for (int a = 0; a < 4; ++a) {
      float4 v;
      v.x = acc[a][0]; v.y = acc[a][1]; v.z = acc[a][2]; v.w = acc[a][3];
      *(float4*)(P0b + (size_t)(row0 + ty * 4 + a) * NN + col0 + tx * 4) = v;
    }
  }
  zred[tid] = zs;
  __syncthreads();
#pragma unroll
  for (int o = 128; o; o >>= 1) {
    if (tid < o) zred[tid] += zred[tid + o];
    __syncthreads();
  }
  if (tid == 0) partZ[(b * 16 + by) * 16 + bx] = zred[0];
}

// ------------------------------------------------------- init r0, B bufs ---
__global__ __launch_bounds__(256) void init_rc_kernel(const double* __restrict__ partZ,
                                                      float* __restrict__ r0,
                                                      double* __restrict__ Binit,
                                                      double* __restrict__ Bzero) {
  const int b = blockIdx.x, tid = threadIdx.x;
  __shared__ double red[256];
  red[tid] = partZ[b * 256 + tid];
  __syncthreads();
#pragma unroll
  for (int o = 128; o; o >>= 1) {
    if (tid < o) red[tid] += red[tid + o];
    __syncthreads();
  }
  const double Z = red[0];
  const float rv = (float)(1.0 / Z);
  for (int i = tid; i < NP1; i += 256) {
    r0[b * NP1 + i] = rv;
    Binit[b * NP1 + i] = (i == NN) ? (double)NN : 1.0;  // so c_0 = ab/Binit = 1
    Bzero[b * NP1 + i] = 0.0;
  }
}

// --------------------------------------------- one Sinkhorn step kernel ----
// R9-proven structure, 4 rows/wave. Body-only P0 (b = id%8 XCD pin).
//   u_i = body_i . c + dv*c_N          -> r'_i = 1/u_i
//   u_N = dv*(sum(c)+c_N)              -> r'_N = N/u_N        (desig block)
//   B_j = colsum(r .* body)_j + r_N*dv (desig adds the r_N*dv term)
//   B_N = dv*(sum(r) + r_N)
// 256 blocks x 512 thr: slab = id/8 (32 rows), 8 waves x 4 rows, float4
// staged (16/lane), loads issued before the prologue. 32 blocks/batch ->
// 262K f64 atomics/step (half of R9).
__global__ __launch_bounds__(512) void step_kernel(const float* __restrict__ P0,
                                                   const float* __restrict__ dustbin,
                                                   const float* __restrict__ rin,
                                                   float* __restrict__ rout,
                                                   const double* __restrict__ Bprev,
                                                   double* __restrict__ Bacc,
                                                   double* __restrict__ Bzero) {
  const int id = blockIdx.x;
  const int b = id & 7;   // XCD pin: batch = bid % 8
  const int s = id >> 3;  // slab 0..31
  const int tid = threadIdx.x;
  const int lane = tid & 63;
  const int wv = tid >> 6;  // 0..7
  const bool desig = (s == 31);

  __shared__ __align__(16) float c_f[NN];
  __shared__ __align__(16) float part_lds[8][NN];
  __shared__ double wredR[8];
  __shared__ double wredC[8];
  __shared__ double cN_sh;

  const float d = dustbin[0];
  const float dv = expf(-5.0f * fminf(fmaxf(-d, -3.0f), 3.0f));
  const double dv_d = (double)dv;

  const float* P0b = P0 + (size_t)b * NN * NN;
  const float* rv_in = rin + b * NP1;
  const int row0 = s * 32 + wv * 4;  // this wave's 4 consecutive rows

  // ---- issue all row loads first (latency hides under prologue) ----
  float4 p[4][4];
  float rw[4];
#pragma unroll
  for (int q = 0; q < 4; ++q) {
    const float4* pr = (const float4*)(P0b + (size_t)(row0 + q) * NN);
#pragma unroll
    for (int k = 0; k < 4; ++k) p[q][k] = pr[lane + (k << 6)];
    rw[q] = rv_in[row0 + q];  // wave-uniform
  }

  // ---- prologue: zero next-step B (256x33 = 8448 >= 8200); c = ab/Bprev ----
  if (tid < 33) {
    const int idx = id * 33 + tid;
    if (idx < NB * NP1) Bzero[idx] = 0.0;
  }
  const double* Bp = Bprev + b * NP1;
  c_f[tid] = (float)(1.0 / Bp[tid]);
  c_f[tid + 512] = (float)(1.0 / Bp[tid + 512]);
  if (tid == 0) cN_sh = (double)NN / Bp[NN];
  __syncthreads();
  const double cN = cN_sh;

  // ---- fused: row dots (f64) + column partials (f32) ----
  double dot[4] = {0.0, 0.0, 0.0, 0.0};
  float4 pk[4];
#pragma unroll
  for (int k = 0; k < 4; ++k) {
    const int j4 = lane + (k << 6);
    const float4 cc = ((const float4*)c_f)[j4];
    const double c0 = (double)cc.x, c1 = (double)cc.y;
    const double c2 = (double)cc.z, c3 = (double)cc.w;
    float4 acc = {0.f, 0.f, 0.f, 0.f};
#pragma unroll
    for (int q = 0; q < 4; ++q) {
      dot[q] += (double)p[q][k].x * c0 + (double)p[q][k].y * c1 +
                (double)p[q][k].z * c2 + (double)p[q][k].w * c3;
      acc.x = fmaf(rw[q], p[q][k].x, acc.x);
      acc.y = fmaf(rw[q], p[q][k].y, acc.y);
      acc.z = fmaf(rw[q], p[q][k].z, acc.z);
      acc.w = fmaf(rw[q], p[q][k].w, acc.w);
    }
    pk[k] = acc;
  }
#pragma unroll
  for (int o = 32; o; o >>= 1) {
#pragma unroll
    for (int q = 0; q < 4; ++q) dot[q] += __shfl_xor(dot[q], o, 64);
  }
  if (lane == 0) {
    float* ro = rout + b * NP1;
#pragma unroll
    for (int q = 0; q < 4; ++q)
      ro[row0 + q] = (float)(1.0 / (dot[q] + dv_d * cN));
    wredR[wv] = ((double)rw[0] + (double)rw[1]) + ((double)rw[2] + (double)rw[3]);
  }
  // per-wave column partials to LDS
  {
    float4* pl4 = (float4*)&part_lds[wv][0];
#pragma unroll
    for (int k = 0; k < 4; ++k) pl4[lane + (k << 6)] = pk[k];
  }
  // block sum(c) in f64 (each thread sums exactly the 2 c's it wrote)
  {
    double cs = (double)c_f[tid] + (double)c_f[tid + 512];
#pragma unroll
    for (int o = 32; o; o >>= 1) cs += __shfl_xor(cs, o, 64);
    if (lane == 0) wredC[wv] = cs;
  }
  __syncthreads();

  // ---- combine partials; one f64 atomic per column ----
  const float rN = rv_in[NN];
  const float rNdv = rN * dv;
  double* Ba = Bacc + b * NP1;
  for (int j = tid; j < NN; j += 512) {
    float s0 = ((part_lds[0][j] + part_lds[1][j]) + (part_lds[2][j] + part_lds[3][j])) +
               ((part_lds[4][j] + part_lds[5][j]) + (part_lds[6][j] + part_lds[7][j]));
    if (desig) s0 += rNdv;  // dustbin-row contribution, added once per batch
    atomicAdd(Ba + j, (double)s0);
  }
  if (tid == 0) {
    double rsum = ((wredR[0] + wredR[1]) + (wredR[2] + wredR[3])) +
                  ((wredR[4] + wredR[5]) + (wredR[6] + wredR[7]));
    if (desig) rsum += (double)rN;
    atomicAdd(Ba + NN, dv_d * rsum);  // B_N = dv * sum(r)
    if (desig) {
      const double sc = ((wredC[0] + wredC[1]) + (wredC[2] + wredC[3])) +
                        ((wredC[4] + wredC[5]) + (wredC[6] + wredC[7])) + cN;
      rout[b * NP1 + NN] = (float)((double)NN / (dv_d * sc));  // r'_N
    }
  }
}

// ----------------------------------------------------- final c from B ------
__global__ __launch_bounds__(256) void cfinal_kernel(const double* __restrict__ Bfin,
                                                     float* __restrict__ cfin) {
  const int b = blockIdx.x;
  for (int j = threadIdx.x; j < NP1; j += 256)
    cfin[b * LDC + j] = (float)(((j == NN) ? (double)NN : 1.0) / Bfin[b * NP1 + j]);
}

// --------------------------------------------------------------- finalize --
// One row per block; body rows from ws (stride 1024), dustbin row/col = dv.
__global__ __launch_bounds__(256) void finalize_kernel(const float* __restrict__ P0,
                                                       const float* __restrict__ dustbin,
                                                       float* __restrict__ Pout,
                                                       const float* __restrict__ rfin,
                                                       const float* __restrict__ cfin) {
  const int bi = blockIdx.x;
  const int b = bi & 7, i = bi >> 3;  // XCD pin
  const int tid = threadIdx.x;
  const float d = dustbin[0];
  const float dv = expf(-5.0f * fminf(fmaxf(-d, -3.0f), 3.0f));
  const float4* cv = (const float4*)(cfin + b * LDC);
  const float cN = cfin[b * LDC + NN];
  float* dst = Pout + (size_t)b * NP1 * NP1 + (size_t)i * NP1;
  const float4 c = cv[tid];
  if (i < NN) {
    const float rv = rfin[b * NP1 + i];
    const float4 p = ((const float4*)(P0 + ((size_t)b * NN + i) * NN))[tid];
    dst[tid * 4 + 0] = rv * p.x * c.x;
    dst[tid * 4 + 1] = rv * p.y * c.y;
    dst[tid * 4 + 2] = rv * p.z * c.z;
    dst[tid * 4 + 3] = rv * p.w * c.w;
    if (tid == 0) dst[NN] = rv * dv * cN;
  } else {
    const float rv = rfin[b * NP1 + NN];
    dst[tid * 4 + 0] = rv * dv * c.x;
    dst[tid * 4 + 1] = rv * dv * c.y;
    dst[tid * 4 + 2] = rv * dv * c.z;
    dst[tid * 4 + 3] = rv * dv * c.w;
    if (tid == 0) dst[NN] = rv * dv * cN;
  }
}

// ---------------------------------------------------------------------------
extern "C" void kernel_launch(void* const* d_in, const int* in_sizes, int n_in,
                              void* d_out, int out_size, void* d_ws, size_t ws_size,
                              hipStream_t stream) {
  const float* fA = (const float*)d_in[0];
  const float* fB = (const float*)d_in[1];
  const float* dustbin = (const float*)d_in[2];

  float* Pout = (float*)d_out;

  float* P0 = (float*)d_ws;                    // [8][1024][1024] f32 body (32 MiB)
  float* rbuf = P0 + (size_t)NB * NN * NN;     // [2][8][1025] f32
  float* cfin = rbuf + 2 * NB * NP1;           // [8][1028] f32
  double* Bbuf = (double*)(((uintptr_t)(cfin + NB * LDC) + 15) & ~(uintptr_t)15);  // [3][8][1025] f64
  double* partZ = Bbuf + 3 * NB * NP1;         // [8][256] f64
  float* invA = (float*)(partZ + NB * 256);    // [8][1024]
  float* invB = invA + NB * NN;                // [8][1024]

  norm_kernel<<<4096, 256, 0, stream>>>(fA, fB, invA, invB);
  gemm_exp_kernel<<<2048, 256, 0, stream>>>(fA, fB, invA, invB, P0, partZ);
  // r_0 -> rbuf[0]; B "prev" for t=0 -> Bbuf[2] (c_0 = 1); zero Bbuf[0]
  init_rc_kernel<<<NB, 256, 0, stream>>>(partZ, rbuf, Bbuf + 2 * NB * NP1, Bbuf);

  // step t: reads r[t%2], B[(t+2)%3]; writes r[(t+1)%2]; accumulates B[t%3];
  //         zeroes B[(t+1)%3] (for step t+1).
  for (int t = 0; t < NSTEPS; ++t) {
    float* rin = rbuf + (t & 1) * NB * NP1;
    float* rout = rbuf + ((t + 1) & 1) * NB * NP1;
    double* Bprev = Bbuf + ((t + 2) % 3) * NB * NP1;
    double* Bacc = Bbuf + (t % 3) * NB * NP1;
    double* Bzero = Bbuf + ((t + 1) % 3) * NB * NP1;
    step_kernel<<<256, 512, 0, stream>>>(P0, dustbin, rin, rout, Bprev, Bacc, Bzero);
  }

  // after t=99: r_100 in rbuf[0]; B_99 (col sums) in Bbuf[99%3=0]
  cfinal_kernel<<<NB, 256, 0, stream>>>(Bbuf, cfin);
  finalize_kernel<<<NB * NP1, 256, 0, stream>>>(P0, dustbin, Pout, rbuf, cfin);
}